// Round 7
// baseline (539.185 us; speedup 1.0000x reference)
//
#include <hip/hip_runtime.h>
#include <hip/hip_bf16.h>
#include <math.h>

#define NN 20000
#define EE 640000
#define NB 157      // buckets of 128 dst nodes
#define BCAP 5120   // per-bucket capacity (mean 4076 + 16 sigma)
#define NBLK 160    // binning blocks per type
#define CHNK 4000   // edges per binning block

typedef float v2f __attribute__((ext_vector_type(2)));
typedef __attribute__((ext_vector_type(8))) short bf16x8;
typedef __attribute__((ext_vector_type(4))) float f32x4;

__device__ __forceinline__ void wave_fence() {
  __builtin_amdgcn_wave_barrier();
  asm volatile("s_waitcnt lgkmcnt(0)" ::: "memory");
  __builtin_amdgcn_wave_barrier();
}

__device__ __forceinline__ unsigned pack_bf2(float a, float b) {
  __hip_bfloat162 h2 = __float22bfloat162_rn(make_float2(a, b));
  return *(unsigned*)&h2;
}
__device__ __forceinline__ float2 unpack_bf2(unsigned v) {
  float2 r;
  unsigned lo = v << 16, hi = v & 0xffff0000u;
  r.x = __uint_as_float(lo);
  r.y = __uint_as_float(hi);
  return r;
}

// ---------------- CSR build pass 1: bin edges by dst>>7 (grid-strided, packed) ----------------
__global__ __launch_bounds__(256) void bin_k(const int* __restrict__ ea,
                                             const int* __restrict__ eb,
                                             int* __restrict__ gcnt,
                                             int* __restrict__ bbuf) {
  int t = blockIdx.y;
  const int* ei = t ? eb : ea;
  int tid = threadIdx.x;
  __shared__ int lh[NB], lbase[NB];
  if (tid < NB) lh[tid] = 0;
  __syncthreads();
  int e0 = blockIdx.x * CHNK;
  int e1 = min(e0 + CHNK, EE);
  int myb[16], myr[16], myv[16];
#pragma unroll
  for (int i = 0; i < 16; ++i) {
    int e = e0 + tid + i * 256;
    if (e < e1) {
      int s = ei[e], d = ei[EE + e];
      int b = d >> 7;
      myb[i] = b;
      myv[i] = (s << 7) | (d & 127);
      myr[i] = atomicAdd(&lh[b], 1);
    } else {
      myb[i] = -1;
    }
  }
  __syncthreads();
  if (tid < NB) {
    int c = lh[tid];
    lbase[tid] = c ? atomicAdd(&gcnt[t * NB + tid], c) : 0;
  }
  __syncthreads();
#pragma unroll
  for (int i = 0; i < 16; ++i) {
    int b = myb[i];
    if (b >= 0) {
      int pos = lbase[b] + myr[i];
      if (pos < BCAP) bbuf[((size_t)t * NB + b) * BCAP + pos] = myv[i];
    }
  }
}

// ---------------- CSR build pass 2a: parallel segmented scan of bucket counts ----------------
__global__ __launch_bounds__(512) void bscan_k(const int* __restrict__ gcnt,
                                               int* __restrict__ bstart) {
  __shared__ int buf[512];
  int tid = threadIdx.x;
  int t = tid >> 8, b = tid & 255;
  int val = (b < NB) ? gcnt[t * NB + b] : 0;
  buf[tid] = val;
  __syncthreads();
  for (int s = 1; s < 256; s <<= 1) {
    int x = ((tid & 255) >= s) ? buf[tid - s] : 0;
    __syncthreads();
    buf[tid] += x;
    __syncthreads();
  }
  if (b < NB) bstart[t * NB + b] = buf[tid] - val;
}

// ---------------- CSR build pass 2b: per-bucket local counting sort ----------------
__global__ __launch_bounds__(256) void build_k(const int* __restrict__ gcnt,
                                               const int* __restrict__ bstart,
                                               const int* __restrict__ bbuf,
                                               int* __restrict__ rowptr,
                                               int* __restrict__ csr) {
  int b = blockIdx.x, t = blockIdx.y;
  int cnt = gcnt[t * NB + b];
  int start = bstart[t * NB + b];
  int n0 = b << 7;
  int nlocal = min(128, NN - n0);
  int tid = threadIdx.x;
  __shared__ int arr[128], lcur[128];
  if (tid < 128) arr[tid] = 0;
  __syncthreads();
  const int* ebuf = bbuf + ((size_t)t * NB + b) * BCAP;
  for (int i = tid; i < cnt; i += 256) atomicAdd(&arr[ebuf[i] & 127], 1);
  __syncthreads();
  int deg = (tid < 128) ? arr[tid] : 0;
  for (int s = 1; s < 128; s <<= 1) {
    int x = (tid < 128 && tid >= s) ? arr[tid - s] : 0;
    __syncthreads();
    if (tid < 128) arr[tid] += x;
    __syncthreads();
  }
  if (tid < nlocal) {
    int incl = arr[tid];
    rowptr[t * (NN + 1) + n0 + tid + 1] = start + incl;
    lcur[tid] = start + incl - deg;
  }
  if (b == 0 && tid == 0) rowptr[t * (NN + 1)] = 0;
  __syncthreads();
  for (int i = tid; i < cnt; i += 256) {
    int v = ebuf[i];
    int pos = atomicAdd(&lcur[v & 127], 1);
    csr[(size_t)t * EE + pos] = v >> 7;
  }
}

// ---------------- fp32 tiled GEMM with optional bf16-packed secondary output ----------------
template <int NT, int BM, int BN, int BK, int TM, int TN>
__global__ __launch_bounds__(NT) void sgemm_k(const float* __restrict__ A,
                                              const float* __restrict__ B,
                                              float* __restrict__ C, int M, int N, int K,
                                              long long Abs, long long Bbs, long long Cbs,
                                              unsigned* __restrict__ Cb, long long Cbb) {
  A += blockIdx.z * Abs; B += blockIdx.z * Bbs; C += blockIdx.z * Cbs;
  if (Cb) Cb += blockIdx.z * Cbb;
  const int bm = blockIdx.x * BM, bn = blockIdx.y * BN;
  __shared__ float As[BK][BM + 4];
  __shared__ float Bs[BK][BN + 4];
  int tid = threadIdx.x;
  constexpr int TX = BN / TN;
  int tx = tid % TX, ty = tid / TX;
  float acc[TM][TN] = {};
  for (int k0 = 0; k0 < K; k0 += BK) {
#pragma unroll
    for (int i = 0; i < (BM * BK) / (NT * 4); ++i) {
      int idx = tid + i * NT;
      int row = idx / (BK / 4), kq = idx % (BK / 4);
      float4 v = make_float4(0.f, 0.f, 0.f, 0.f);
      int gr = bm + row;
      if (gr < M) v = *(const float4*)&A[(size_t)gr * K + k0 + kq * 4];
      As[kq * 4 + 0][row] = v.x; As[kq * 4 + 1][row] = v.y;
      As[kq * 4 + 2][row] = v.z; As[kq * 4 + 3][row] = v.w;
    }
#pragma unroll
    for (int i = 0; i < (BK * BN) / (NT * 4); ++i) {
      int idx = tid + i * NT;
      int row = idx / (BN / 4), cq = idx % (BN / 4);
      *(float4*)&Bs[row][cq * 4] = *(const float4*)&B[(size_t)(k0 + row) * N + bn + cq * 4];
    }
    __syncthreads();
#pragma unroll
    for (int k = 0; k < BK; ++k) {
      float a[TM], b[TN];
#pragma unroll
      for (int i = 0; i < TM; i += 4) *(float4*)&a[i] = *(float4*)&As[k][ty * TM + i];
#pragma unroll
      for (int j = 0; j < TN; j += 4) *(float4*)&b[j] = *(float4*)&Bs[k][tx * TN + j];
#pragma unroll
      for (int i = 0; i < TM; ++i)
#pragma unroll
        for (int j = 0; j < TN; ++j) acc[i][j] += a[i] * b[j];
    }
    __syncthreads();
  }
#pragma unroll
  for (int i = 0; i < TM; ++i) {
    int gr = bm + ty * TM + i;
    if (gr < M) {
#pragma unroll
      for (int j = 0; j < TN; j += 4)
        *(float4*)&C[(size_t)gr * N + bn + tx * TN + j] = *(float4*)&acc[i][j];
      if (Cb) {
#pragma unroll
        for (int j = 0; j < TN; j += 2)
          Cb[(size_t)gr * (N >> 1) + ((bn + tx * TN + j) >> 1)] = pack_bf2(acc[i][j], acc[i][j + 1]);
      }
    }
  }
}

// ---------------- layer-1 attention scores from h1 ----------------
template <int C>
__global__ void score_k(const float* __restrict__ hf, const float* __restrict__ as_,
                        const float* __restrict__ ad_, float* __restrict__ ss,
                        float* __restrict__ sd) {
  int idx = blockIdx.x * 256 + threadIdx.x;
  if (idx >= 2 * NN * 8) return;
  int t = idx / (NN * 8), r = idx % (NN * 8), n = r / 8, hh = r % 8;
  const int HC = 8 * C;
  const float* hrow = hf + (size_t)t * NN * HC + (size_t)n * HC + hh * C;
  const float* a1 = as_ + t * HC + hh * C;
  const float* a2 = ad_ + t * HC + hh * C;
  float s1 = 0.f, s2 = 0.f;
#pragma unroll
  for (int c = 0; c < C; c += 4) {
    float4 f = *(const float4*)&hrow[c];
    float4 u = *(const float4*)&a1[c];
    float4 w = *(const float4*)&a2[c];
    s1 += f.x * u.x + f.y * u.y + f.z * u.z + f.w * u.w;
    s2 += f.x * w.x + f.y * w.y + f.z * w.z + f.w * w.w;
  }
  ss[idx] = s1; sd[idx] = s2;
}

__device__ __forceinline__ float lrelu(float v) { return v > 0.f ? v : 0.2f * v; }

// ---------------- MFMA-based aggregation (both layers), bf16 operands, plain LDS ----------------
// Uses ONLY conventions hardware-verified by the passing gemm2_k (bf16 16x16x32):
//   A-frag: lane l elem j = A[l&15][(l>>4)*8+j]; B-frag: lane l elem j = B[(l>>4)*8+j][l&15];
//   D: lane l reg r = C[(l>>4)*4+r][l&15].
// Per wave: one (dst node n, type t). Per 32-edge tile:
//   E[16 rows (8 heads + 8 zero)][32 edges] x V[32 edges][128 ch] -> D[16][128] via
//   8x mfma_f32_16x16x32_bf16.
// A operand: ET[row 16][edge 32] u16 (stride 40) (ds b128 of 8 consecutive u16).
// B operand: VT[c 128][k 32] bf16, row stride 17 words. Word i of row c = edges (2i,2i+1).
//   Lane l reads words (ct*16+(l&15))*17 + (l>>4)*4 + {0..3} -> elem j = V[(l>>4)*8+j][col].
//   Phase B gathers row words (lane = channel pair) and writes the transpose via VALU packs.
// MODE 0 (layer 1): V = h1b (PER-TYPE: vsrc += t*NN*64); out = diag D[ch>>4][ch]*iz -> fp32 o1.
// MODE 1 (layer 2): V = hmidb (shared, no offset); out = D[h][ch]*iz[h] -> packed bf16 aggp.
template <int MODE>
__global__ __launch_bounds__(256) void aggm_k(const int* __restrict__ rowptr,
                                              const int* __restrict__ csr,
                                              const float* __restrict__ ssrc,
                                              const float* __restrict__ sdst,
                                              const unsigned* __restrict__ vsrc,
                                              float* __restrict__ out1,
                                              unsigned* __restrict__ out2) {
  int t = blockIdx.y;
  rowptr += t * (NN + 1); csr += (size_t)t * EE;
  ssrc += (size_t)t * NN * 8; sdst += (size_t)t * NN * 8;
  if (MODE == 0) {
    out1 += (size_t)t * NN * 128;
    vsrc += (size_t)t * NN * 64;   // h1b is per-type (the R2-R6 lost line)
  } else {
    out2 += (size_t)t * NN * 512;  // hmidb is shared across types
  }
  int tid = threadIdx.x, w = tid >> 6, lane = tid & 63;
  int lg = lane >> 4;
  int n = blockIdx.x * 4 + w;
  int row = rowptr[n], end = rowptr[n + 1];
  __shared__ __align__(16) unsigned VTw[4][2176];        // 128 rows x 17 words
  __shared__ __align__(16) unsigned short ET[4][640];    // 16 rows x 40 (32 used)
  __shared__ __align__(16) int sidx[4][32];
  // one-time init: VT finite (stale x zero-E = 0, never NaN); ET rows 8-15 stay 0;
  // sidx valid offsets (stale reads in ragged tail groups stay in-bounds).
  for (int i = lane; i < 2176; i += 64) VTw[w][i] = 0;
  for (int i = lane; i < 640; i += 64) ET[w][i] = 0;
  if (lane < 32) sidx[w][lane] = 0;
  float4 sda = *(const float4*)&sdst[(size_t)n * 8];
  float4 sdb = *(const float4*)&sdst[(size_t)n * 8 + 4];
  float z[8];
#pragma unroll
  for (int i = 0; i < 8; ++i) z[i] = 0.f;
  f32x4 acc[8];
#pragma unroll
  for (int i = 0; i < 8; ++i) acc[i] = (f32x4){0.f, 0.f, 0.f, 0.f};
  unsigned* VTp = &VTw[w][0];
  const unsigned lane4 = lane << 2;
  const unsigned wr0 = (unsigned)(2 * lane) * 17u;   // word base of row 2*lane
  const char* hbc = (const char*)vsrc;
  for (int base = row; base < end; base += 32) {
    int cnt = min(32, end - base);
    // ---- phase A: per-edge exp weights -> E^T in LDS (bf16), z from rounded values ----
    if (lane < 32) {
      float4 ea = {0.f, 0.f, 0.f, 0.f}, eb = {0.f, 0.f, 0.f, 0.f};
      if (lane < cnt) {
        int s = csr[base + lane];
        sidx[w][lane] = s << 8;   // byte offset (64 words/row)
        float4 pa = *(const float4*)&ssrc[(size_t)s * 8];
        float4 pb = *(const float4*)&ssrc[(size_t)s * 8 + 4];
        ea.x = __expf(lrelu(pa.x + sda.x)); ea.y = __expf(lrelu(pa.y + sda.y));
        ea.z = __expf(lrelu(pa.z + sda.z)); ea.w = __expf(lrelu(pa.w + sda.w));
        eb.x = __expf(lrelu(pb.x + sdb.x)); eb.y = __expf(lrelu(pb.y + sdb.y));
        eb.z = __expf(lrelu(pb.z + sdb.z)); eb.w = __expf(lrelu(pb.w + sdb.w));
      }
      unsigned p0 = pack_bf2(ea.x, ea.y), p1 = pack_bf2(ea.z, ea.w);
      unsigned p2 = pack_bf2(eb.x, eb.y), p3 = pack_bf2(eb.z, eb.w);
      float2 q0 = unpack_bf2(p0), q1 = unpack_bf2(p1);
      float2 q2 = unpack_bf2(p2), q3 = unpack_bf2(p3);
      z[0] += q0.x; z[1] += q0.y; z[2] += q1.x; z[3] += q1.y;
      z[4] += q2.x; z[5] += q2.y; z[6] += q3.x; z[7] += q3.y;
      unsigned short* et = &ET[w][lane];
      et[0]   = (unsigned short)p0;  et[40]  = (unsigned short)(p0 >> 16);
      et[80]  = (unsigned short)p1;  et[120] = (unsigned short)(p1 >> 16);
      et[160] = (unsigned short)p2;  et[200] = (unsigned short)(p2 >> 16);
      et[240] = (unsigned short)p3;  et[280] = (unsigned short)(p3 >> 16);
    }
    wave_fence();
    // ---- phase B: gather V rows, write transposed into VT (lane owns ch 2l, 2l+1) ----
    for (int g = 0; g < cnt; g += 4) {
      unsigned off[4];
      *(int4*)&off[0] = *(const int4*)&sidx[w][g];   // stale entries stay valid
      unsigned u0 = *(const unsigned*)(hbc + (off[0] | lane4));
      unsigned u1 = *(const unsigned*)(hbc + (off[1] | lane4));
      unsigned u2 = *(const unsigned*)(hbc + (off[2] | lane4));
      unsigned u3 = *(const unsigned*)(hbc + (off[3] | lane4));
      unsigned lo01 = (u0 & 0xffffu) | (u1 << 16);
      unsigned lo23 = (u2 & 0xffffu) | (u3 << 16);
      unsigned hi01 = (u0 >> 16) | (u1 & 0xffff0000u);
      unsigned hi23 = (u2 >> 16) | (u3 & 0xffff0000u);
      unsigned r0 = wr0 + (unsigned)(g >> 1);
      VTp[r0] = lo01; VTp[r0 + 1] = lo23;
      VTp[r0 + 17] = hi01; VTp[r0 + 18] = hi23;
    }
    wave_fence();
    // ---- phase C: A from ET, B from VT (plain ds reads), 8 MFMAs ----
    bf16x8 af = *(const bf16x8*)&ET[w][(lane & 15) * 40 + lg * 8];
#pragma unroll
    for (int ct = 0; ct < 8; ++ct) {
      const unsigned* vp = VTp + (unsigned)((ct * 16 + (lane & 15)) * 17 + lg * 4);
      uint4 bv = make_uint4(vp[0], vp[1], vp[2], vp[3]);
      bf16x8 bf = *(const bf16x8*)&bv;
      acc[ct] = __builtin_amdgcn_mfma_f32_16x16x32_bf16(af, bf, acc[ct], 0, 0, 0);
    }
    wave_fence();
  }
  // ---- z reduce over the wave (high lanes contributed zeros) ----
#pragma unroll
  for (int off = 32; off; off >>= 1) {
#pragma unroll
    for (int i = 0; i < 8; ++i) z[i] += __shfl_xor(z[i], off);
  }
  float iz[8];
#pragma unroll
  for (int i = 0; i < 8; ++i) iz[i] = z[i] > 0.f ? 1.f / z[i] : 0.f;
  if (MODE == 0) {
    int col = lane & 15;
    if (lg == 0) {
#pragma unroll
      for (int q = 0; q < 4; ++q)
        out1[(size_t)n * 128 + q * 16 + col] = acc[q][q] * iz[q];
    } else if (lg == 1) {
#pragma unroll
      for (int q = 0; q < 4; ++q)
        out1[(size_t)n * 128 + (4 + q) * 16 + col] = acc[4 + q][q] * iz[4 + q];
    }
  } else {
    int colp = (lane & 15) >> 1;
    bool wr = (lane & 1) == 0;
    if (lg == 0) {
#pragma unroll
      for (int ct = 0; ct < 8; ++ct) {
#pragma unroll
        for (int r = 0; r < 4; ++r) {
          float v = acc[ct][r] * iz[r];
          float v2 = __shfl_xor(v, 1);
          if (wr) out2[(size_t)n * 512 + r * 64 + ct * 8 + colp] = pack_bf2(v, v2);
        }
      }
    } else if (lg == 1) {
#pragma unroll
      for (int ct = 0; ct < 8; ++ct) {
#pragma unroll
        for (int r = 0; r < 4; ++r) {
          float v = acc[ct][r] * iz[4 + r];
          float v2 = __shfl_xor(v, 1);
          if (wr) out2[(size_t)n * 512 + (4 + r) * 64 + ct * 8 + colp] = pack_bf2(v, v2);
        }
      }
    }
  }
}

// ---------------- hetero-mean + bias + ELU (layer 1), writes fp32 + packed bf16 ----------------
__global__ void combine1_k(const float* __restrict__ oa, const float* __restrict__ ob,
                           const float* __restrict__ b1, float* __restrict__ hmid,
                           unsigned* __restrict__ hmidb) {
  int idx = blockIdx.x * 256 + threadIdx.x;
  if (idx >= NN * 64) return;
  int n = idx >> 6, j2 = idx & 63, j = j2 * 2;
  float2 va = *(const float2*)&oa[(size_t)n * 128 + j];
  float2 vb = *(const float2*)&ob[(size_t)n * 128 + j];
  float vx = 0.5f * ((va.x + b1[j]) + (vb.x + b1[128 + j]));
  float vy = 0.5f * ((va.y + b1[j + 1]) + (vb.y + b1[128 + j + 1]));
  vx = vx > 0.f ? vx : (__expf(vx) - 1.f);
  vy = vy > 0.f ? vy : (__expf(vy) - 1.f);
  *(float2*)&hmid[(size_t)n * 128 + j] = make_float2(vx, vy);
  hmidb[idx] = pack_bf2(vx, vy);
}

// ---------------- layer-2 folds ----------------
__global__ void fold2_k(const float* __restrict__ W2, const float* __restrict__ a2s,
                        const float* __restrict__ a2d, float* __restrict__ wsf,
                        float* __restrict__ wdf) {
  int idx = blockIdx.x * 256 + threadIdx.x;
  if (idx >= 2048) return;
  int t = idx >> 10, r = idx & 1023, hh = r >> 7, k = r & 127;
  const float* wrow = W2 + (size_t)t * 65536 + (size_t)k * 512 + hh * 64;
  const float* as = a2s + t * 512 + hh * 64;
  const float* ad = a2d + t * 512 + hh * 64;
  float s1 = 0.f, s2 = 0.f;
  for (int c = 0; c < 64; ++c) { s1 += wrow[c] * as[c]; s2 += wrow[c] * ad[c]; }
  wsf[idx] = s1; wdf[idx] = s2;
}

// fold W2 into transposed, bf16-packed MFMA B operand: BTp[t][col 64][k 1024 (512 words)]
__global__ void foldBT_k(const float* __restrict__ W2, unsigned* __restrict__ BTp) {
  int idx = blockIdx.x * 256 + threadIdx.x;
  if (idx >= 65536) return;
  int t = idx >> 15, r = idx & 32767, c = r >> 9, kw = r & 511;
  int K0 = kw * 2, K1 = K0 + 1;
  int hh0 = K0 >> 7, kk0 = K0 & 127;
  int hh1 = K1 >> 7, kk1 = K1 & 127;
  float v0 = 0.125f * W2[(size_t)t * 65536 + (size_t)kk0 * 512 + hh0 * 64 + c];
  float v1 = 0.125f * W2[(size_t)t * 65536 + (size_t)kk1 * 512 + hh1 * 64 + c];
  BTp[idx] = pack_bf2(v0, v1);
}

// ---------------- layer-2 scores from hmid ----------------
__global__ void score2_k(const float* __restrict__ hmid, const float* __restrict__ wsf,
                         const float* __restrict__ wdf, float* __restrict__ ss,
                         float* __restrict__ sdo) {
  int idx = blockIdx.x * 256 + threadIdx.x;
  if (idx >= NN * 8) return;
  int n = idx >> 3, hh = idx & 7;
  const float* hm = hmid + (size_t)n * 128;
  const float* w0s = wsf + (size_t)hh * 128;
  const float* w0d = wdf + (size_t)hh * 128;
  const float* w1s = wsf + (size_t)(8 + hh) * 128;
  const float* w1d = wdf + (size_t)(8 + hh) * 128;
  float s0s = 0.f, s0d = 0.f, s1s = 0.f, s1d = 0.f;
#pragma unroll
  for (int c = 0; c < 128; c += 4) {
    float4 f = *(const float4*)&hm[c];
    float4 a = *(const float4*)&w0s[c];
    float4 b = *(const float4*)&w0d[c];
    float4 u = *(const float4*)&w1s[c];
    float4 v = *(const float4*)&w1d[c];
    s0s += f.x * a.x + f.y * a.y + f.z * a.z + f.w * a.w;
    s0d += f.x * b.x + f.y * b.y + f.z * b.z + f.w * b.w;
    s1s += f.x * u.x + f.y * u.y + f.z * u.z + f.w * u.w;
    s1d += f.x * v.x + f.y * v.y + f.z * v.z + f.w * v.w;
  }
  ss[idx] = s0s; sdo[idx] = s0d;
  ss[NN * 8 + idx] = s1s; sdo[NN * 8 + idx] = s1d;
}

// ---------------- layer-2 GEMM via MFMA: feat = ELU(0.5*(Aa*Ba + Ab*Bb + ba + bb)) ----------------
__global__ __launch_bounds__(256) void gemm2_k(const unsigned* __restrict__ Ap,
                                               const unsigned* __restrict__ BT,
                                               const float* __restrict__ b2,
                                               float* __restrict__ feat) {
  int tid = threadIdx.x, w = tid >> 6, l = tid & 63;
  int lr = l & 15, lgq = l >> 4;
  int rowbase = blockIdx.x * 64 + w * 16;
  int arow = rowbase + lr;
  if (arow > NN - 1) arow = NN - 1;   // clamp: garbage-free load, store is guarded
  f32x4 acc0 = {0.f, 0.f, 0.f, 0.f}, acc1 = acc0, acc2 = acc0, acc3 = acc0;
#pragma unroll
  for (int t = 0; t < 2; ++t) {
    const unsigned* ap = Ap + (size_t)t * NN * 512 + (size_t)arow * 512 + lgq * 4;
    const unsigned* bp = BT + t * 32768 + lr * 512 + lgq * 4;
    for (int kw = 0; kw < 512; kw += 16) {   // 32 k-elements per step
      uint4 av = *(const uint4*)(ap + kw);
      uint4 bv0 = *(const uint4*)(bp + kw);
      uint4 bv1 = *(const uint4*)(bp + 16 * 512 + kw);
      uint4 bv2 = *(const uint4*)(bp + 32 * 512 + kw);
      uint4 bv3 = *(const uint4*)(bp + 48 * 512 + kw);
      bf16x8 afq = *(const bf16x8*)&av;
      acc0 = __builtin_amdgcn_mfma_f32_16x16x32_bf16(afq, *(const bf16x8*)&bv0, acc0, 0, 0, 0);
      acc1 = __builtin_amdgcn_mfma_f32_16x16x32_bf16(afq, *(const bf16x8*)&bv1, acc1, 0, 0, 0);
      acc2 = __builtin_amdgcn_mfma_f32_16x16x32_bf16(afq, *(const bf16x8*)&bv2, acc2, 0, 0, 0);
      acc3 = __builtin_amdgcn_mfma_f32_16x16x32_bf16(afq, *(const bf16x8*)&bv3, acc3, 0, 0, 0);
    }
  }
  f32x4 accs[4] = {acc0, acc1, acc2, acc3};
#pragma unroll
  for (int ct = 0; ct < 4; ++ct) {
    int col = ct * 16 + lr;
    float bsum = b2[col] + b2[64 + col];
#pragma unroll
    for (int r = 0; r < 4; ++r) {
      int rowq = rowbase + lgq * 4 + r;
      if (rowq < NN) {
        float v = 0.5f * (accs[ct][r] + bsum);
        v = v > 0.f ? v : (__expf(v) - 1.f);
        feat[(size_t)rowq * 64 + col] = v;
      }
    }
  }
}

// ---------------- classifier ----------------
__global__ __launch_bounds__(256) void cls_k(const float* __restrict__ feat,
                                             const float* __restrict__ Wc1,
                                             const float* __restrict__ bc1,
                                             const float* __restrict__ Wc2,
                                             const float* __restrict__ bc2,
                                             float* __restrict__ out) {
  __shared__ float w1[64 * 32];
  __shared__ float w2[64];
  __shared__ float b1s[32], b2s[2];
  __shared__ float fs[8 * 64];
  __shared__ float hs[8 * 32];
  int tid = threadIdx.x;
  for (int i = tid; i < 2048; i += 256) w1[i] = Wc1[i];
  if (tid < 64) w2[tid] = Wc2[tid];
  if (tid < 32) b1s[tid] = bc1[tid];
  if (tid < 2) b2s[tid] = bc2[tid];
  int nbase = blockIdx.x * 8;
  for (int i = tid; i < 512; i += 256) fs[i] = feat[(size_t)nbase * 64 + i];
  __syncthreads();
  int local = tid >> 5, tt = tid & 31;
  const float* f = fs + local * 64;
  float acc = b1s[tt];
#pragma unroll
  for (int c = 0; c < 64; ++c) acc += f[c] * w1[c * 32 + tt];
  hs[local * 32 + tt] = fmaxf(acc, 0.f);
  __syncthreads();
  if (tid < 16) {
    int l = tid >> 1, j = tid & 1;
    float o = b2s[j];
#pragma unroll
    for (int i = 0; i < 32; ++i) o += hs[l * 32 + i] * w2[i * 2 + j];
    out[(size_t)(nbase + l) * 2 + j] = o;
  }
}

extern "C" void kernel_launch(void* const* d_in, const int* in_sizes, int n_in,
                              void* d_out, int out_size, void* d_ws, size_t ws_size,
                              hipStream_t stream) {
  const float* x   = (const float*)d_in[0];
  const int* eia   = (const int*)d_in[1];
  const int* eib   = (const int*)d_in[2];
  const float* W1  = (const float*)d_in[3];
  const float* a1s = (const float*)d_in[4];
  const float* a1d = (const float*)d_in[5];
  const float* b1  = (const float*)d_in[6];
  const float* W2  = (const float*)d_in[7];
  const float* a2s = (const float*)d_in[8];
  const float* a2d = (const float*)d_in[9];
  const float* b2  = (const float*)d_in[10];
  const float* Wc1 = (const float*)d_in[11];
  const float* bc1 = (const float*)d_in[12];
  const float* Wc2 = (const float*)d_in[13];
  const float* bc2 = (const float*)d_in[14];
  float* out = (float*)d_out;

  char* ws = (char*)d_ws;
  size_t off = 0;
  auto alloc = [&](size_t bytes) -> char* {
    char* p = ws + off;
    off += (bytes + 255) & ~(size_t)255;
    return p;
  };
  int* gcnt       = (int*)alloc((size_t)2 * NB * 4);
  int* bstart     = (int*)alloc((size_t)2 * NB * 4);
  int* bbuf       = (int*)alloc((size_t)2 * NB * BCAP * 4);
  int* rowptr     = (int*)alloc((size_t)2 * (NN + 1) * 4);
  int* csr        = (int*)alloc((size_t)2 * EE * 4);
  float* h1       = (float*)alloc((size_t)2 * NN * 128 * 4);
  unsigned* h1b   = (unsigned*)alloc((size_t)2 * NN * 64 * 4);
  float* s1s      = (float*)alloc((size_t)2 * NN * 8 * 4);
  float* s1d      = (float*)alloc((size_t)2 * NN * 8 * 4);
  float* o1       = (float*)alloc((size_t)2 * NN * 128 * 4);
  float* hmid     = (float*)alloc((size_t)NN * 128 * 4);
  unsigned* hmidb = (unsigned*)alloc((size_t)NN * 64 * 4);
  float* wsf      = (float*)alloc((size_t)2048 * 4);
  float* wdf      = (float*)alloc((size_t)2048 * 4);
  unsigned* BTp   = (unsigned*)alloc((size_t)65536 * 4);   // bf16-packed transposed fold
  float* s2s      = (float*)alloc((size_t)2 * NN * 8 * 4);
  float* s2d      = (float*)alloc((size_t)2 * NN * 8 * 4);
  unsigned* aggp  = (unsigned*)alloc((size_t)2 * NN * 512 * 4);  // bf16-packed agg, both types
  float* feat     = (float*)alloc((size_t)NN * 64 * 4);

  // CSR build: bucketed two-pass (grid-strided binning, packed entries)
  hipMemsetAsync(gcnt, 0, (size_t)2 * NB * 4, stream);
  bin_k<<<dim3(NBLK, 2), 256, 0, stream>>>(eia, eib, gcnt, bbuf);
  bscan_k<<<1, 512, 0, stream>>>(gcnt, bstart);
  build_k<<<dim3(NB, 2), 256, 0, stream>>>(gcnt, bstart, bbuf, rowptr, csr);

  // layer-2 weight folds (independent of layer 1; launch early)
  fold2_k<<<8, 256, 0, stream>>>(W2, a2s, a2d, wsf, wdf);
  foldBT_k<<<256, 256, 0, stream>>>(W2, BTp);

  // layer 1 (GEMM writes fp32 h1 + packed bf16 h1b in epilogue)
  sgemm_k<256, 64, 64, 32, 4, 4><<<dim3((NN + 63) / 64, 2, 2), 256, 0, stream>>>(
      x, W1, h1, NN, 128, 256, 0LL, 256LL * 128, (long long)NN * 128, h1b, (long long)NN * 64);
  score_k<16><<<(2 * NN * 8 + 255) / 256, 256, 0, stream>>>(h1, a1s, a1d, s1s, s1d);
  aggm_k<0><<<dim3(NN / 4, 2), 256, 0, stream>>>(rowptr, csr, s1s, s1d, h1b, o1, nullptr);
  combine1_k<<<(NN * 64 + 255) / 256, 256, 0, stream>>>(o1, o1 + (size_t)NN * 128, b1, hmid, hmidb);

  // layer 2: scores, MFMA aggregation (bf16 out), fused MFMA GEMM + combine + ELU
  score2_k<<<(NN * 8 + 255) / 256, 256, 0, stream>>>(hmid, wsf, wdf, s2s, s2d);
  aggm_k<1><<<dim3(NN / 4, 2), 256, 0, stream>>>(rowptr, csr, s2s, s2d, hmidb, nullptr, aggp);
  gemm2_k<<<(NN + 63) / 64, 256, 0, stream>>>(aggp, BTp, b2, feat);

  // classifier
  cls_k<<<NN / 8, 256, 0, stream>>>(feat, Wc1, bc1, Wc2, bc2, out);
}

// Round 8
// 454.277 us; speedup vs baseline: 1.1869x; 1.1869x over previous
//
#include <hip/hip_runtime.h>
#include <hip/hip_bf16.h>
#include <math.h>

#define NN 20000
#define EE 640000
#define NB 157      // buckets of 128 dst nodes
#define BCAP 5120   // per-bucket capacity (mean 4076 + 16 sigma)
#define NBLK 160    // binning blocks per type
#define CHNK 4000   // edges per binning block

typedef float v2f __attribute__((ext_vector_type(2)));
typedef __attribute__((ext_vector_type(8))) short bf16x8;
typedef __attribute__((ext_vector_type(4))) float f32x4;

__device__ __forceinline__ void wave_fence() {
  __builtin_amdgcn_wave_barrier();
  asm volatile("s_waitcnt lgkmcnt(0)" ::: "memory");
  __builtin_amdgcn_wave_barrier();
}

__device__ __forceinline__ unsigned pack_bf2(float a, float b) {
  __hip_bfloat162 h2 = __float22bfloat162_rn(make_float2(a, b));
  return *(unsigned*)&h2;
}
__device__ __forceinline__ float2 unpack_bf2(unsigned v) {
  float2 r;
  unsigned lo = v << 16, hi = v & 0xffff0000u;
  r.x = __uint_as_float(lo);
  r.y = __uint_as_float(hi);
  return r;
}

// ---------------- CSR build pass 1: bin edges by dst>>7 (grid-strided, packed) ----------------
__global__ __launch_bounds__(256) void bin_k(const int* __restrict__ ea,
                                             const int* __restrict__ eb,
                                             int* __restrict__ gcnt,
                                             int* __restrict__ bbuf) {
  int t = blockIdx.y;
  const int* ei = t ? eb : ea;
  int tid = threadIdx.x;
  __shared__ int lh[NB], lbase[NB];
  if (tid < NB) lh[tid] = 0;
  __syncthreads();
  int e0 = blockIdx.x * CHNK;
  int e1 = min(e0 + CHNK, EE);
  int myb[16], myr[16], myv[16];
#pragma unroll
  for (int i = 0; i < 16; ++i) {
    int e = e0 + tid + i * 256;
    if (e < e1) {
      int s = ei[e], d = ei[EE + e];
      int b = d >> 7;
      myb[i] = b;
      myv[i] = (s << 7) | (d & 127);
      myr[i] = atomicAdd(&lh[b], 1);
    } else {
      myb[i] = -1;
    }
  }
  __syncthreads();
  if (tid < NB) {
    int c = lh[tid];
    lbase[tid] = c ? atomicAdd(&gcnt[t * NB + tid], c) : 0;
  }
  __syncthreads();
#pragma unroll
  for (int i = 0; i < 16; ++i) {
    int b = myb[i];
    if (b >= 0) {
      int pos = lbase[b] + myr[i];
      if (pos < BCAP) bbuf[((size_t)t * NB + b) * BCAP + pos] = myv[i];
    }
  }
}

// ---------------- CSR build pass 2a: parallel segmented scan of bucket counts ----------------
__global__ __launch_bounds__(512) void bscan_k(const int* __restrict__ gcnt,
                                               int* __restrict__ bstart) {
  __shared__ int buf[512];
  int tid = threadIdx.x;
  int t = tid >> 8, b = tid & 255;
  int val = (b < NB) ? gcnt[t * NB + b] : 0;
  buf[tid] = val;
  __syncthreads();
  for (int s = 1; s < 256; s <<= 1) {
    int x = ((tid & 255) >= s) ? buf[tid - s] : 0;
    __syncthreads();
    buf[tid] += x;
    __syncthreads();
  }
  if (b < NB) bstart[t * NB + b] = buf[tid] - val;
}

// ---------------- CSR build pass 2b: per-bucket local counting sort ----------------
__global__ __launch_bounds__(256) void build_k(const int* __restrict__ gcnt,
                                               const int* __restrict__ bstart,
                                               const int* __restrict__ bbuf,
                                               int* __restrict__ rowptr,
                                               int* __restrict__ csr) {
  int b = blockIdx.x, t = blockIdx.y;
  int cnt = gcnt[t * NB + b];
  int start = bstart[t * NB + b];
  int n0 = b << 7;
  int nlocal = min(128, NN - n0);
  int tid = threadIdx.x;
  __shared__ int arr[128], lcur[128];
  if (tid < 128) arr[tid] = 0;
  __syncthreads();
  const int* ebuf = bbuf + ((size_t)t * NB + b) * BCAP;
  for (int i = tid; i < cnt; i += 256) atomicAdd(&arr[ebuf[i] & 127], 1);
  __syncthreads();
  int deg = (tid < 128) ? arr[tid] : 0;
  for (int s = 1; s < 128; s <<= 1) {
    int x = (tid < 128 && tid >= s) ? arr[tid - s] : 0;
    __syncthreads();
    if (tid < 128) arr[tid] += x;
    __syncthreads();
  }
  if (tid < nlocal) {
    int incl = arr[tid];
    rowptr[t * (NN + 1) + n0 + tid + 1] = start + incl;
    lcur[tid] = start + incl - deg;
  }
  if (b == 0 && tid == 0) rowptr[t * (NN + 1)] = 0;
  __syncthreads();
  for (int i = tid; i < cnt; i += 256) {
    int v = ebuf[i];
    int pos = atomicAdd(&lcur[v & 127], 1);
    csr[(size_t)t * EE + pos] = v >> 7;
  }
}

// ---------------- fp32 tiled GEMM with optional bf16-packed secondary output ----------------
template <int NT, int BM, int BN, int BK, int TM, int TN>
__global__ __launch_bounds__(NT) void sgemm_k(const float* __restrict__ A,
                                              const float* __restrict__ B,
                                              float* __restrict__ C, int M, int N, int K,
                                              long long Abs, long long Bbs, long long Cbs,
                                              unsigned* __restrict__ Cb, long long Cbb) {
  A += blockIdx.z * Abs; B += blockIdx.z * Bbs; C += blockIdx.z * Cbs;
  if (Cb) Cb += blockIdx.z * Cbb;
  const int bm = blockIdx.x * BM, bn = blockIdx.y * BN;
  __shared__ float As[BK][BM + 4];
  __shared__ float Bs[BK][BN + 4];
  int tid = threadIdx.x;
  constexpr int TX = BN / TN;
  int tx = tid % TX, ty = tid / TX;
  float acc[TM][TN] = {};
  for (int k0 = 0; k0 < K; k0 += BK) {
#pragma unroll
    for (int i = 0; i < (BM * BK) / (NT * 4); ++i) {
      int idx = tid + i * NT;
      int row = idx / (BK / 4), kq = idx % (BK / 4);
      float4 v = make_float4(0.f, 0.f, 0.f, 0.f);
      int gr = bm + row;
      if (gr < M) v = *(const float4*)&A[(size_t)gr * K + k0 + kq * 4];
      As[kq * 4 + 0][row] = v.x; As[kq * 4 + 1][row] = v.y;
      As[kq * 4 + 2][row] = v.z; As[kq * 4 + 3][row] = v.w;
    }
#pragma unroll
    for (int i = 0; i < (BK * BN) / (NT * 4); ++i) {
      int idx = tid + i * NT;
      int row = idx / (BN / 4), cq = idx % (BN / 4);
      *(float4*)&Bs[row][cq * 4] = *(const float4*)&B[(size_t)(k0 + row) * N + bn + cq * 4];
    }
    __syncthreads();
#pragma unroll
    for (int k = 0; k < BK; ++k) {
      float a[TM], b[TN];
#pragma unroll
      for (int i = 0; i < TM; i += 4) *(float4*)&a[i] = *(float4*)&As[k][ty * TM + i];
#pragma unroll
      for (int j = 0; j < TN; j += 4) *(float4*)&b[j] = *(float4*)&Bs[k][tx * TN + j];
#pragma unroll
      for (int i = 0; i < TM; ++i)
#pragma unroll
        for (int j = 0; j < TN; ++j) acc[i][j] += a[i] * b[j];
    }
    __syncthreads();
  }
#pragma unroll
  for (int i = 0; i < TM; ++i) {
    int gr = bm + ty * TM + i;
    if (gr < M) {
#pragma unroll
      for (int j = 0; j < TN; j += 4)
        *(float4*)&C[(size_t)gr * N + bn + tx * TN + j] = *(float4*)&acc[i][j];
      if (Cb) {
#pragma unroll
        for (int j = 0; j < TN; j += 2)
          Cb[(size_t)gr * (N >> 1) + ((bn + tx * TN + j) >> 1)] = pack_bf2(acc[i][j], acc[i][j + 1]);
      }
    }
  }
}

// ---------------- layer-1 attention scores from h1 ----------------
template <int C>
__global__ void score_k(const float* __restrict__ hf, const float* __restrict__ as_,
                        const float* __restrict__ ad_, float* __restrict__ ss,
                        float* __restrict__ sd) {
  int idx = blockIdx.x * 256 + threadIdx.x;
  if (idx >= 2 * NN * 8) return;
  int t = idx / (NN * 8), r = idx % (NN * 8), n = r / 8, hh = r % 8;
  const int HC = 8 * C;
  const float* hrow = hf + (size_t)t * NN * HC + (size_t)n * HC + hh * C;
  const float* a1 = as_ + t * HC + hh * C;
  const float* a2 = ad_ + t * HC + hh * C;
  float s1 = 0.f, s2 = 0.f;
#pragma unroll
  for (int c = 0; c < C; c += 4) {
    float4 f = *(const float4*)&hrow[c];
    float4 u = *(const float4*)&a1[c];
    float4 w = *(const float4*)&a2[c];
    s1 += f.x * u.x + f.y * u.y + f.z * u.z + f.w * u.w;
    s2 += f.x * w.x + f.y * w.y + f.z * w.z + f.w * w.w;
  }
  ss[idx] = s1; sd[idx] = s2;
}

__device__ __forceinline__ float lrelu(float v) { return v > 0.f ? v : 0.2f * v; }

// ---------------- layer-1 aggregation: wave per node, 8-deep pipelined bf16 gather ----------------
__global__ __launch_bounds__(256) void aggw1_k(const int* __restrict__ rowptr,
                                               const int* __restrict__ csr,
                                               const float* __restrict__ ssrc,
                                               const float* __restrict__ sdst,
                                               const unsigned* __restrict__ hb,
                                               float* __restrict__ out) {
  int t = blockIdx.y;
  rowptr += t * (NN + 1); csr += (size_t)t * EE;
  ssrc += (size_t)t * NN * 8; sdst += (size_t)t * NN * 8;
  hb += (size_t)t * NN * 64; out += (size_t)t * NN * 128;
  int tid = threadIdx.x, w = tid >> 6, lane = tid & 63;
  int n = blockIdx.x * 4 + w;
  int row = rowptr[n], end = rowptr[n + 1];
  __shared__ __align__(16) int sidx[4][64];
  __shared__ __align__(16) float sexp[4][64][8];
  float4 sda = *(const float4*)&sdst[(size_t)n * 8];
  float4 sdb = *(const float4*)&sdst[(size_t)n * 8 + 4];
  float za_x = 0.f, za_y = 0.f, za_z = 0.f, za_w = 0.f;
  float zb_x = 0.f, zb_y = 0.f, zb_z = 0.f, zb_w = 0.f;
  int hme = lane >> 3;
  unsigned lane4 = lane << 2;
  const char* hbc = (const char*)hb;
  v2f acc = {0.f, 0.f};
  for (int base = row; base < end; base += 64) {
    int cnt = min(64, end - base);
    if (lane < cnt) {
      int s = csr[base + lane];
      sidx[w][lane] = s << 8;            // byte offset into hb (64 words/row)
      float4 pa = *(const float4*)&ssrc[(size_t)s * 8];
      float4 pb = *(const float4*)&ssrc[(size_t)s * 8 + 4];
      float4 ea, eb;
      ea.x = __expf(lrelu(pa.x + sda.x)); ea.y = __expf(lrelu(pa.y + sda.y));
      ea.z = __expf(lrelu(pa.z + sda.z)); ea.w = __expf(lrelu(pa.w + sda.w));
      eb.x = __expf(lrelu(pb.x + sdb.x)); eb.y = __expf(lrelu(pb.y + sdb.y));
      eb.z = __expf(lrelu(pb.z + sdb.z)); eb.w = __expf(lrelu(pb.w + sdb.w));
      za_x += ea.x; za_y += ea.y; za_z += ea.z; za_w += ea.w;
      zb_x += eb.x; zb_y += eb.y; zb_z += eb.z; zb_w += eb.w;
      *(float4*)&sexp[w][lane][0] = ea;
      *(float4*)&sexp[w][lane][4] = eb;
    }
    wave_fence();
    int g = 0;
    for (; g + 8 <= cnt; g += 8) {
      unsigned off[8];
      *(int4*)&off[0] = *(const int4*)&sidx[w][g];
      *(int4*)&off[4] = *(const int4*)&sidx[w][g + 4];
      unsigned uv[8];
#pragma unroll
      for (int j = 0; j < 8; ++j)
        uv[j] = *(const unsigned*)(hbc + (off[j] | lane4));   // 8 gathers in flight
#pragma unroll
      for (int j = 0; j < 8; ++j) {
        float a = sexp[w][g + j][hme];
        float2 vf = unpack_bf2(uv[j]);
        v2f v = {vf.x, vf.y};
        acc += a * v;
      }
    }
    for (; g < cnt; ++g) {
      unsigned off = (unsigned)sidx[w][g];
      unsigned uvr = *(const unsigned*)(hbc + (off | lane4));
      float a = sexp[w][g][hme];
      float2 vf = unpack_bf2(uvr);
      v2f v = {vf.x, vf.y};
      acc += a * v;
    }
    wave_fence();
  }
#pragma unroll
  for (int off = 32; off; off >>= 1) {
    za_x += __shfl_xor(za_x, off); za_y += __shfl_xor(za_y, off);
    za_z += __shfl_xor(za_z, off); za_w += __shfl_xor(za_w, off);
    zb_x += __shfl_xor(zb_x, off); zb_y += __shfl_xor(zb_y, off);
    zb_z += __shfl_xor(zb_z, off); zb_w += __shfl_xor(zb_w, off);
  }
  float zh[8] = {za_x, za_y, za_z, za_w, zb_x, zb_y, zb_z, zb_w};
  float z = zh[hme];
  float iz = z > 0.f ? 1.f / z : 0.f;
  *(float2*)&out[(size_t)n * 128 + lane * 2] = make_float2(acc.x * iz, acc.y * iz);
}

// ---------------- hetero-mean + bias + ELU (layer 1), writes fp32 + packed bf16 ----------------
__global__ void combine1_k(const float* __restrict__ oa, const float* __restrict__ ob,
                           const float* __restrict__ b1, float* __restrict__ hmid,
                           unsigned* __restrict__ hmidb) {
  int idx = blockIdx.x * 256 + threadIdx.x;
  if (idx >= NN * 64) return;
  int n = idx >> 6, j2 = idx & 63, j = j2 * 2;
  float2 va = *(const float2*)&oa[(size_t)n * 128 + j];
  float2 vb = *(const float2*)&ob[(size_t)n * 128 + j];
  float vx = 0.5f * ((va.x + b1[j]) + (vb.x + b1[128 + j]));
  float vy = 0.5f * ((va.y + b1[j + 1]) + (vb.y + b1[128 + j + 1]));
  vx = vx > 0.f ? vx : (__expf(vx) - 1.f);
  vy = vy > 0.f ? vy : (__expf(vy) - 1.f);
  *(float2*)&hmid[(size_t)n * 128 + j] = make_float2(vx, vy);
  hmidb[idx] = pack_bf2(vx, vy);
}

// ---------------- layer-2 folds ----------------
__global__ void fold2_k(const float* __restrict__ W2, const float* __restrict__ a2s,
                        const float* __restrict__ a2d, float* __restrict__ wsf,
                        float* __restrict__ wdf) {
  int idx = blockIdx.x * 256 + threadIdx.x;
  if (idx >= 2048) return;
  int t = idx >> 10, r = idx & 1023, hh = r >> 7, k = r & 127;
  const float* wrow = W2 + (size_t)t * 65536 + (size_t)k * 512 + hh * 64;
  const float* as = a2s + t * 512 + hh * 64;
  const float* ad = a2d + t * 512 + hh * 64;
  float s1 = 0.f, s2 = 0.f;
  for (int c = 0; c < 64; ++c) { s1 += wrow[c] * as[c]; s2 += wrow[c] * ad[c]; }
  wsf[idx] = s1; wdf[idx] = s2;
}

// fold W2 into transposed, bf16-packed MFMA B operand: BTp[t][col 64][k 1024 (512 words)]
__global__ void foldBT_k(const float* __restrict__ W2, unsigned* __restrict__ BTp) {
  int idx = blockIdx.x * 256 + threadIdx.x;
  if (idx >= 65536) return;
  int t = idx >> 15, r = idx & 32767, c = r >> 9, kw = r & 511;
  int K0 = kw * 2, K1 = K0 + 1;
  int hh0 = K0 >> 7, kk0 = K0 & 127;
  int hh1 = K1 >> 7, kk1 = K1 & 127;
  float v0 = 0.125f * W2[(size_t)t * 65536 + (size_t)kk0 * 512 + hh0 * 64 + c];
  float v1 = 0.125f * W2[(size_t)t * 65536 + (size_t)kk1 * 512 + hh1 * 64 + c];
  BTp[idx] = pack_bf2(v0, v1);
}

// ---------------- layer-2 scores from hmid ----------------
__global__ void score2_k(const float* __restrict__ hmid, const float* __restrict__ wsf,
                         const float* __restrict__ wdf, float* __restrict__ ss,
                         float* __restrict__ sdo) {
  int idx = blockIdx.x * 256 + threadIdx.x;
  if (idx >= NN * 8) return;
  int n = idx >> 3, hh = idx & 7;
  const float* hm = hmid + (size_t)n * 128;
  const float* w0s = wsf + (size_t)hh * 128;
  const float* w0d = wdf + (size_t)hh * 128;
  const float* w1s = wsf + (size_t)(8 + hh) * 128;
  const float* w1d = wdf + (size_t)(8 + hh) * 128;
  float s0s = 0.f, s0d = 0.f, s1s = 0.f, s1d = 0.f;
#pragma unroll
  for (int c = 0; c < 128; c += 4) {
    float4 f = *(const float4*)&hm[c];
    float4 a = *(const float4*)&w0s[c];
    float4 b = *(const float4*)&w0d[c];
    float4 u = *(const float4*)&w1s[c];
    float4 v = *(const float4*)&w1d[c];
    s0s += f.x * a.x + f.y * a.y + f.z * a.z + f.w * a.w;
    s0d += f.x * b.x + f.y * b.y + f.z * b.z + f.w * b.w;
    s1s += f.x * u.x + f.y * u.y + f.z * u.z + f.w * u.w;
    s1d += f.x * v.x + f.y * v.y + f.z * v.z + f.w * v.w;
  }
  ss[idx] = s0s; sdo[idx] = s0d;
  ss[NN * 8 + idx] = s1s; sdo[NN * 8 + idx] = s1d;
}

// ---------------- layer-2 aggregation: wave per node, readlane E-broadcast (no LDS) ----------------
// Lane e holds edge e's 8 exp-weights bf16-packed in p0..p3 + byte offset soff.
// Inner loop: 5 uniform readlanes/edge -> SGPR broadcast; FMAs on VALU; no LDS, no fences.
__global__ __launch_bounds__(256) void aggw2_k(const int* __restrict__ rowptr,
                                               const int* __restrict__ csr,
                                               const float* __restrict__ ssrc,
                                               const float* __restrict__ sdst,
                                               const unsigned* __restrict__ hmidb,
                                               unsigned* __restrict__ aggp) {
  int t = blockIdx.y;
  rowptr += t * (NN + 1); csr += (size_t)t * EE;
  ssrc += (size_t)t * NN * 8; sdst += (size_t)t * NN * 8;
  aggp += (size_t)t * NN * 512;
  int tid = threadIdx.x, lane = tid & 63;
  int n = blockIdx.x * 4 + (tid >> 6);
  int row = rowptr[n], end = rowptr[n + 1];
  float4 sda = *(const float4*)&sdst[(size_t)n * 8];
  float4 sdb = *(const float4*)&sdst[(size_t)n * 8 + 4];
  float z0 = 0.f, z1 = 0.f, z2 = 0.f, z3 = 0.f;
  float z4 = 0.f, z5 = 0.f, z6 = 0.f, z7 = 0.f;
  unsigned lane4 = lane << 2;
  const char* hbc = (const char*)hmidb;
  v2f acc[8];
#pragma unroll
  for (int i = 0; i < 8; ++i) acc[i] = (v2f){0.f, 0.f};
  for (int base = row; base < end; base += 64) {
    int cnt = min(64, end - base);
    unsigned p0 = 0, p1 = 0, p2 = 0, p3 = 0;
    int soff = 0;
    if (lane < cnt) {
      int s = csr[base + lane];
      soff = s << 8;                       // byte offset (64 words/row)
      float4 pa = *(const float4*)&ssrc[(size_t)s * 8];
      float4 pb = *(const float4*)&ssrc[(size_t)s * 8 + 4];
      float4 ea, eb;
      ea.x = __expf(lrelu(pa.x + sda.x)); ea.y = __expf(lrelu(pa.y + sda.y));
      ea.z = __expf(lrelu(pa.z + sda.z)); ea.w = __expf(lrelu(pa.w + sda.w));
      eb.x = __expf(lrelu(pb.x + sdb.x)); eb.y = __expf(lrelu(pb.y + sdb.y));
      eb.z = __expf(lrelu(pb.z + sdb.z)); eb.w = __expf(lrelu(pb.w + sdb.w));
      p0 = pack_bf2(ea.x, ea.y); p1 = pack_bf2(ea.z, ea.w);
      p2 = pack_bf2(eb.x, eb.y); p3 = pack_bf2(eb.z, eb.w);
      float2 q0 = unpack_bf2(p0), q1 = unpack_bf2(p1);
      float2 q2 = unpack_bf2(p2), q3 = unpack_bf2(p3);
      z0 += q0.x; z1 += q0.y; z2 += q1.x; z3 += q1.y;
      z4 += q2.x; z5 += q2.y; z6 += q3.x; z7 += q3.y;
    }
    int g = 0;
    for (; g + 8 <= cnt; g += 8) {
      unsigned uv[8];
#pragma unroll
      for (int j = 0; j < 8; ++j) {
        unsigned off = (unsigned)__builtin_amdgcn_readlane(soff, g + j);
        uv[j] = *(const unsigned*)(hbc + (off | lane4));   // 8 gathers in flight
      }
#pragma unroll
      for (int j = 0; j < 8; ++j) {
        int e = g + j;
        float2 E0 = unpack_bf2((unsigned)__builtin_amdgcn_readlane((int)p0, e));
        float2 E1 = unpack_bf2((unsigned)__builtin_amdgcn_readlane((int)p1, e));
        float2 E2 = unpack_bf2((unsigned)__builtin_amdgcn_readlane((int)p2, e));
        float2 E3 = unpack_bf2((unsigned)__builtin_amdgcn_readlane((int)p3, e));
        float2 vf = unpack_bf2(uv[j]);
        v2f v = {vf.x, vf.y};
        acc[0] += E0.x * v;
        acc[1] += E0.y * v;
        acc[2] += E1.x * v;
        acc[3] += E1.y * v;
        acc[4] += E2.x * v;
        acc[5] += E2.y * v;
        acc[6] += E3.x * v;
        acc[7] += E3.y * v;
      }
    }
    for (; g < cnt; ++g) {
      unsigned off = (unsigned)__builtin_amdgcn_readlane(soff, g);
      unsigned uvr = *(const unsigned*)(hbc + (off | lane4));
      float2 E0 = unpack_bf2((unsigned)__builtin_amdgcn_readlane((int)p0, g));
      float2 E1 = unpack_bf2((unsigned)__builtin_amdgcn_readlane((int)p1, g));
      float2 E2 = unpack_bf2((unsigned)__builtin_amdgcn_readlane((int)p2, g));
      float2 E3 = unpack_bf2((unsigned)__builtin_amdgcn_readlane((int)p3, g));
      float2 vf = unpack_bf2(uvr);
      v2f v = {vf.x, vf.y};
      acc[0] += E0.x * v;
      acc[1] += E0.y * v;
      acc[2] += E1.x * v;
      acc[3] += E1.y * v;
      acc[4] += E2.x * v;
      acc[5] += E2.y * v;
      acc[6] += E3.x * v;
      acc[7] += E3.y * v;
    }
  }
#pragma unroll
  for (int off = 32; off; off >>= 1) {
    z0 += __shfl_xor(z0, off); z1 += __shfl_xor(z1, off);
    z2 += __shfl_xor(z2, off); z3 += __shfl_xor(z3, off);
    z4 += __shfl_xor(z4, off); z5 += __shfl_xor(z5, off);
    z6 += __shfl_xor(z6, off); z7 += __shfl_xor(z7, off);
  }
  float zh[8] = {z0, z1, z2, z3, z4, z5, z6, z7};
#pragma unroll
  for (int i = 0; i < 8; ++i) {
    float z = zh[i];
    float iz = z > 0.f ? 1.f / z : 0.f;
    aggp[(size_t)n * 512 + i * 64 + lane] = pack_bf2(acc[i].x * iz, acc[i].y * iz);
  }
}

// ---------------- layer-2 GEMM via MFMA: feat = ELU(0.5*(Aa*Ba + Ab*Bb + ba + bb)) ----------------
__global__ __launch_bounds__(256) void gemm2_k(const unsigned* __restrict__ Ap,
                                               const unsigned* __restrict__ BT,
                                               const float* __restrict__ b2,
                                               float* __restrict__ feat) {
  int tid = threadIdx.x, w = tid >> 6, l = tid & 63;
  int lr = l & 15, lgq = l >> 4;
  int rowbase = blockIdx.x * 64 + w * 16;
  int arow = rowbase + lr;
  if (arow > NN - 1) arow = NN - 1;   // clamp: garbage-free load, store is guarded
  f32x4 acc0 = {0.f, 0.f, 0.f, 0.f}, acc1 = acc0, acc2 = acc0, acc3 = acc0;
#pragma unroll
  for (int t = 0; t < 2; ++t) {
    const unsigned* ap = Ap + (size_t)t * NN * 512 + (size_t)arow * 512 + lgq * 4;
    const unsigned* bp = BT + t * 32768 + lr * 512 + lgq * 4;
    for (int kw = 0; kw < 512; kw += 16) {   // 32 k-elements per step
      uint4 av = *(const uint4*)(ap + kw);
      uint4 bv0 = *(const uint4*)(bp + kw);
      uint4 bv1 = *(const uint4*)(bp + 16 * 512 + kw);
      uint4 bv2 = *(const uint4*)(bp + 32 * 512 + kw);
      uint4 bv3 = *(const uint4*)(bp + 48 * 512 + kw);
      bf16x8 afq = *(const bf16x8*)&av;
      acc0 = __builtin_amdgcn_mfma_f32_16x16x32_bf16(afq, *(const bf16x8*)&bv0, acc0, 0, 0, 0);
      acc1 = __builtin_amdgcn_mfma_f32_16x16x32_bf16(afq, *(const bf16x8*)&bv1, acc1, 0, 0, 0);
      acc2 = __builtin_amdgcn_mfma_f32_16x16x32_bf16(afq, *(const bf16x8*)&bv2, acc2, 0, 0, 0);
      acc3 = __builtin_amdgcn_mfma_f32_16x16x32_bf16(afq, *(const bf16x8*)&bv3, acc3, 0, 0, 0);
    }
  }
  f32x4 accs[4] = {acc0, acc1, acc2, acc3};
#pragma unroll
  for (int ct = 0; ct < 4; ++ct) {
    int col = ct * 16 + lr;
    float bsum = b2[col] + b2[64 + col];
#pragma unroll
    for (int r = 0; r < 4; ++r) {
      int rowq = rowbase + lgq * 4 + r;
      if (rowq < NN) {
        float v = 0.5f * (accs[ct][r] + bsum);
        v = v > 0.f ? v : (__expf(v) - 1.f);
        feat[(size_t)rowq * 64 + col] = v;
      }
    }
  }
}

// ---------------- classifier ----------------
__global__ __launch_bounds__(256) void cls_k(const float* __restrict__ feat,
                                             const float* __restrict__ Wc1,
                                             const float* __restrict__ bc1,
                                             const float* __restrict__ Wc2,
                                             const float* __restrict__ bc2,
                                             float* __restrict__ out) {
  __shared__ float w1[64 * 32];
  __shared__ float w2[64];
  __shared__ float b1s[32], b2s[2];
  __shared__ float fs[8 * 64];
  __shared__ float hs[8 * 32];
  int tid = threadIdx.x;
  for (int i = tid; i < 2048; i += 256) w1[i] = Wc1[i];
  if (tid < 64) w2[tid] = Wc2[tid];
  if (tid < 32) b1s[tid] = bc1[tid];
  if (tid < 2) b2s[tid] = bc2[tid];
  int nbase = blockIdx.x * 8;
  for (int i = tid; i < 512; i += 256) fs[i] = feat[(size_t)nbase * 64 + i];
  __syncthreads();
  int local = tid >> 5, tt = tid & 31;
  const float* f = fs + local * 64;
  float acc = b1s[tt];
#pragma unroll
  for (int c = 0; c < 64; ++c) acc += f[c] * w1[c * 32 + tt];
  hs[local * 32 + tt] = fmaxf(acc, 0.f);
  __syncthreads();
  if (tid < 16) {
    int l = tid >> 1, j = tid & 1;
    float o = b2s[j];
#pragma unroll
    for (int i = 0; i < 32; ++i) o += hs[l * 32 + i] * w2[i * 2 + j];
    out[(size_t)(nbase + l) * 2 + j] = o;
  }
}

extern "C" void kernel_launch(void* const* d_in, const int* in_sizes, int n_in,
                              void* d_out, int out_size, void* d_ws, size_t ws_size,
                              hipStream_t stream) {
  const float* x   = (const float*)d_in[0];
  const int* eia   = (const int*)d_in[1];
  const int* eib   = (const int*)d_in[2];
  const float* W1  = (const float*)d_in[3];
  const float* a1s = (const float*)d_in[4];
  const float* a1d = (const float*)d_in[5];
  const float* b1  = (const float*)d_in[6];
  const float* W2  = (const float*)d_in[7];
  const float* a2s = (const float*)d_in[8];
  const float* a2d = (const float*)d_in[9];
  const float* b2  = (const float*)d_in[10];
  const float* Wc1 = (const float*)d_in[11];
  const float* bc1 = (const float*)d_in[12];
  const float* Wc2 = (const float*)d_in[13];
  const float* bc2 = (const float*)d_in[14];
  float* out = (float*)d_out;

  char* ws = (char*)d_ws;
  size_t off = 0;
  auto alloc = [&](size_t bytes) -> char* {
    char* p = ws + off;
    off += (bytes + 255) & ~(size_t)255;
    return p;
  };
  int* gcnt       = (int*)alloc((size_t)2 * NB * 4);
  int* bstart     = (int*)alloc((size_t)2 * NB * 4);
  int* bbuf       = (int*)alloc((size_t)2 * NB * BCAP * 4);
  int* rowptr     = (int*)alloc((size_t)2 * (NN + 1) * 4);
  int* csr        = (int*)alloc((size_t)2 * EE * 4);
  float* h1       = (float*)alloc((size_t)2 * NN * 128 * 4);
  unsigned* h1b   = (unsigned*)alloc((size_t)2 * NN * 64 * 4);
  float* s1s      = (float*)alloc((size_t)2 * NN * 8 * 4);
  float* s1d      = (float*)alloc((size_t)2 * NN * 8 * 4);
  float* o1       = (float*)alloc((size_t)2 * NN * 128 * 4);
  float* hmid     = (float*)alloc((size_t)NN * 128 * 4);
  unsigned* hmidb = (unsigned*)alloc((size_t)NN * 64 * 4);
  float* wsf      = (float*)alloc((size_t)2048 * 4);
  float* wdf      = (float*)alloc((size_t)2048 * 4);
  unsigned* BTp   = (unsigned*)alloc((size_t)65536 * 4);   // bf16-packed transposed fold
  float* s2s      = (float*)alloc((size_t)2 * NN * 8 * 4);
  float* s2d      = (float*)alloc((size_t)2 * NN * 8 * 4);
  unsigned* aggp  = (unsigned*)alloc((size_t)2 * NN * 512 * 4);  // bf16-packed agg, both types
  float* feat     = (float*)alloc((size_t)NN * 64 * 4);

  // CSR build: bucketed two-pass (grid-strided binning, packed entries)
  hipMemsetAsync(gcnt, 0, (size_t)2 * NB * 4, stream);
  bin_k<<<dim3(NBLK, 2), 256, 0, stream>>>(eia, eib, gcnt, bbuf);
  bscan_k<<<1, 512, 0, stream>>>(gcnt, bstart);
  build_k<<<dim3(NB, 2), 256, 0, stream>>>(gcnt, bstart, bbuf, rowptr, csr);

  // layer-2 weight folds (independent of layer 1; launch early)
  fold2_k<<<8, 256, 0, stream>>>(W2, a2s, a2d, wsf, wdf);
  foldBT_k<<<256, 256, 0, stream>>>(W2, BTp);

  // layer 1 (GEMM writes fp32 h1 + packed bf16 h1b in epilogue)
  sgemm_k<256, 64, 64, 32, 4, 4><<<dim3((NN + 63) / 64, 2, 2), 256, 0, stream>>>(
      x, W1, h1, NN, 128, 256, 0LL, 256LL * 128, (long long)NN * 128, h1b, (long long)NN * 64);
  score_k<16><<<(2 * NN * 8 + 255) / 256, 256, 0, stream>>>(h1, a1s, a1d, s1s, s1d);
  aggw1_k<<<dim3(NN / 4, 2), 256, 0, stream>>>(rowptr, csr, s1s, s1d, h1b, o1);
  combine1_k<<<(NN * 64 + 255) / 256, 256, 0, stream>>>(o1, o1 + (size_t)NN * 128, b1, hmid, hmidb);

  // layer 2: scores, readlane-broadcast aggregation (bf16 out), fused MFMA GEMM + combine + ELU
  score2_k<<<(NN * 8 + 255) / 256, 256, 0, stream>>>(hmid, wsf, wdf, s2s, s2d);
  aggw2_k<<<dim3(NN / 4, 2), 256, 0, stream>>>(rowptr, csr, s2s, s2d, hmidb, aggp);
  gemm2_k<<<(NN + 63) / 64, 256, 0, stream>>>(aggp, BTp, b2, feat);

  // classifier
  cls_k<<<NN / 8, 256, 0, stream>>>(feat, Wc1, bc1, Wc2, bc2, out);
}

// Round 9
// 431.791 us; speedup vs baseline: 1.2487x; 1.0521x over previous
//
#include <hip/hip_runtime.h>
#include <hip/hip_bf16.h>
#include <math.h>

#define NN 20000
#define EE 640000
#define NB 157      // buckets of 128 dst nodes
#define BCAP 5120   // per-bucket capacity (mean 4076 + 16 sigma)
#define NBLK 160    // binning blocks per type
#define CHNK 4000   // edges per binning block

typedef float v2f __attribute__((ext_vector_type(2)));
typedef __attribute__((ext_vector_type(8))) short bf16x8;
typedef __attribute__((ext_vector_type(4))) float f32x4;

__device__ __forceinline__ void wave_fence() {
  __builtin_amdgcn_wave_barrier();
  asm volatile("s_waitcnt lgkmcnt(0)" ::: "memory");
  __builtin_amdgcn_wave_barrier();
}

__device__ __forceinline__ unsigned pack_bf2(float a, float b) {
  __hip_bfloat162 h2 = __float22bfloat162_rn(make_float2(a, b));
  return *(unsigned*)&h2;
}
__device__ __forceinline__ float2 unpack_bf2(unsigned v) {
  float2 r;
  unsigned lo = v << 16, hi = v & 0xffff0000u;
  r.x = __uint_as_float(lo);
  r.y = __uint_as_float(hi);
  return r;
}

// ---------------- CSR build pass 1: bin edges by dst>>7 (grid-strided, packed) ----------------
__global__ __launch_bounds__(256) void bin_k(const int* __restrict__ ea,
                                             const int* __restrict__ eb,
                                             int* __restrict__ gcnt,
                                             int* __restrict__ bbuf) {
  int t = blockIdx.y;
  const int* ei = t ? eb : ea;
  int tid = threadIdx.x;
  __shared__ int lh[NB], lbase[NB];
  if (tid < NB) lh[tid] = 0;
  __syncthreads();
  int e0 = blockIdx.x * CHNK;
  int e1 = min(e0 + CHNK, EE);
  int myb[16], myr[16], myv[16];
#pragma unroll
  for (int i = 0; i < 16; ++i) {
    int e = e0 + tid + i * 256;
    if (e < e1) {
      int s = ei[e], d = ei[EE + e];
      int b = d >> 7;
      myb[i] = b;
      myv[i] = (s << 7) | (d & 127);
      myr[i] = atomicAdd(&lh[b], 1);
    } else {
      myb[i] = -1;
    }
  }
  __syncthreads();
  if (tid < NB) {
    int c = lh[tid];
    lbase[tid] = c ? atomicAdd(&gcnt[t * NB + tid], c) : 0;
  }
  __syncthreads();
#pragma unroll
  for (int i = 0; i < 16; ++i) {
    int b = myb[i];
    if (b >= 0) {
      int pos = lbase[b] + myr[i];
      if (pos < BCAP) bbuf[((size_t)t * NB + b) * BCAP + pos] = myv[i];
    }
  }
}

// ---------------- CSR build pass 2a: parallel segmented scan of bucket counts ----------------
__global__ __launch_bounds__(512) void bscan_k(const int* __restrict__ gcnt,
                                               int* __restrict__ bstart) {
  __shared__ int buf[512];
  int tid = threadIdx.x;
  int t = tid >> 8, b = tid & 255;
  int val = (b < NB) ? gcnt[t * NB + b] : 0;
  buf[tid] = val;
  __syncthreads();
  for (int s = 1; s < 256; s <<= 1) {
    int x = ((tid & 255) >= s) ? buf[tid - s] : 0;
    __syncthreads();
    buf[tid] += x;
    __syncthreads();
  }
  if (b < NB) bstart[t * NB + b] = buf[tid] - val;
}

// ---------------- CSR build pass 2b: per-bucket local counting sort ----------------
__global__ __launch_bounds__(256) void build_k(const int* __restrict__ gcnt,
                                               const int* __restrict__ bstart,
                                               const int* __restrict__ bbuf,
                                               int* __restrict__ rowptr,
                                               int* __restrict__ csr) {
  int b = blockIdx.x, t = blockIdx.y;
  int cnt = gcnt[t * NB + b];
  int start = bstart[t * NB + b];
  int n0 = b << 7;
  int nlocal = min(128, NN - n0);
  int tid = threadIdx.x;
  __shared__ int arr[128], lcur[128];
  if (tid < 128) arr[tid] = 0;
  __syncthreads();
  const int* ebuf = bbuf + ((size_t)t * NB + b) * BCAP;
  for (int i = tid; i < cnt; i += 256) atomicAdd(&arr[ebuf[i] & 127], 1);
  __syncthreads();
  int deg = (tid < 128) ? arr[tid] : 0;
  for (int s = 1; s < 128; s <<= 1) {
    int x = (tid < 128 && tid >= s) ? arr[tid - s] : 0;
    __syncthreads();
    if (tid < 128) arr[tid] += x;
    __syncthreads();
  }
  if (tid < nlocal) {
    int incl = arr[tid];
    rowptr[t * (NN + 1) + n0 + tid + 1] = start + incl;
    lcur[tid] = start + incl - deg;
  }
  if (b == 0 && tid == 0) rowptr[t * (NN + 1)] = 0;
  __syncthreads();
  for (int i = tid; i < cnt; i += 256) {
    int v = ebuf[i];
    int pos = atomicAdd(&lcur[v & 127], 1);
    csr[(size_t)t * EE + pos] = v >> 7;
  }
}

// ---------------- fp32 tiled GEMM; fp32 C optional, bf16-packed secondary output ----------------
template <int NT, int BM, int BN, int BK, int TM, int TN>
__global__ __launch_bounds__(NT) void sgemm_k(const float* __restrict__ A,
                                              const float* __restrict__ B,
                                              float* __restrict__ C, int M, int N, int K,
                                              long long Abs, long long Bbs, long long Cbs,
                                              unsigned* __restrict__ Cb, long long Cbb) {
  A += blockIdx.z * Abs; B += blockIdx.z * Bbs;
  if (C) C += blockIdx.z * Cbs;
  if (Cb) Cb += blockIdx.z * Cbb;
  const int bm = blockIdx.x * BM, bn = blockIdx.y * BN;
  __shared__ float As[BK][BM + 4];
  __shared__ float Bs[BK][BN + 4];
  int tid = threadIdx.x;
  constexpr int TX = BN / TN;
  int tx = tid % TX, ty = tid / TX;
  float acc[TM][TN] = {};
  for (int k0 = 0; k0 < K; k0 += BK) {
#pragma unroll
    for (int i = 0; i < (BM * BK) / (NT * 4); ++i) {
      int idx = tid + i * NT;
      int row = idx / (BK / 4), kq = idx % (BK / 4);
      float4 v = make_float4(0.f, 0.f, 0.f, 0.f);
      int gr = bm + row;
      if (gr < M) v = *(const float4*)&A[(size_t)gr * K + k0 + kq * 4];
      As[kq * 4 + 0][row] = v.x; As[kq * 4 + 1][row] = v.y;
      As[kq * 4 + 2][row] = v.z; As[kq * 4 + 3][row] = v.w;
    }
#pragma unroll
    for (int i = 0; i < (BK * BN) / (NT * 4); ++i) {
      int idx = tid + i * NT;
      int row = idx / (BN / 4), cq = idx % (BN / 4);
      *(float4*)&Bs[row][cq * 4] = *(const float4*)&B[(size_t)(k0 + row) * N + bn + cq * 4];
    }
    __syncthreads();
#pragma unroll
    for (int k = 0; k < BK; ++k) {
      float a[TM], b[TN];
#pragma unroll
      for (int i = 0; i < TM; i += 4) *(float4*)&a[i] = *(float4*)&As[k][ty * TM + i];
#pragma unroll
      for (int j = 0; j < TN; j += 4) *(float4*)&b[j] = *(float4*)&Bs[k][tx * TN + j];
#pragma unroll
      for (int i = 0; i < TM; ++i)
#pragma unroll
        for (int j = 0; j < TN; ++j) acc[i][j] += a[i] * b[j];
    }
    __syncthreads();
  }
#pragma unroll
  for (int i = 0; i < TM; ++i) {
    int gr = bm + ty * TM + i;
    if (gr < M) {
      if (C) {
#pragma unroll
        for (int j = 0; j < TN; j += 4)
          *(float4*)&C[(size_t)gr * N + bn + tx * TN + j] = *(float4*)&acc[i][j];
      }
      if (Cb) {
#pragma unroll
        for (int j = 0; j < TN; j += 2)
          Cb[(size_t)gr * (N >> 1) + ((bn + tx * TN + j) >> 1)] = pack_bf2(acc[i][j], acc[i][j + 1]);
      }
    }
  }
}

// ---------------- layer-1 attention scores from bf16-packed h1b ----------------
__global__ void scoreb_k(const unsigned* __restrict__ hb, const float* __restrict__ as_,
                         const float* __restrict__ ad_, float* __restrict__ ss,
                         float* __restrict__ sd) {
  int idx = blockIdx.x * 256 + threadIdx.x;
  if (idx >= 2 * NN * 8) return;
  int t = idx / (NN * 8), r = idx % (NN * 8), n = r / 8, hh = r % 8;
  const unsigned* hrow = hb + (size_t)t * NN * 64 + (size_t)n * 64 + hh * 8;
  const float* a1 = as_ + t * 128 + hh * 16;
  const float* a2 = ad_ + t * 128 + hh * 16;
  uint4 u0 = *(const uint4*)&hrow[0];
  uint4 u1 = *(const uint4*)&hrow[4];
  unsigned uu[8] = {u0.x, u0.y, u0.z, u0.w, u1.x, u1.y, u1.z, u1.w};
  float s1 = 0.f, s2 = 0.f;
#pragma unroll
  for (int q = 0; q < 8; ++q) {
    float2 f = unpack_bf2(uu[q]);
    s1 += f.x * a1[2 * q] + f.y * a1[2 * q + 1];
    s2 += f.x * a2[2 * q] + f.y * a2[2 * q + 1];
  }
  ss[idx] = s1; sd[idx] = s2;
}

__device__ __forceinline__ float lrelu(float v) { return v > 0.f ? v : 0.2f * v; }

// ---------------- layer-1 aggregation: wave per node, 8-deep pipelined bf16 gather ----------------
__global__ __launch_bounds__(256) void aggw1_k(const int* __restrict__ rowptr,
                                               const int* __restrict__ csr,
                                               const float* __restrict__ ssrc,
                                               const float* __restrict__ sdst,
                                               const unsigned* __restrict__ hb,
                                               float* __restrict__ out) {
  int t = blockIdx.y;
  rowptr += t * (NN + 1); csr += (size_t)t * EE;
  ssrc += (size_t)t * NN * 8; sdst += (size_t)t * NN * 8;
  hb += (size_t)t * NN * 64; out += (size_t)t * NN * 128;
  int tid = threadIdx.x, w = tid >> 6, lane = tid & 63;
  int n = blockIdx.x * 4 + w;
  int row = rowptr[n], end = rowptr[n + 1];
  __shared__ __align__(16) int sidx[4][64];
  __shared__ __align__(16) float sexp[4][64][8];
  float4 sda = *(const float4*)&sdst[(size_t)n * 8];
  float4 sdb = *(const float4*)&sdst[(size_t)n * 8 + 4];
  float za_x = 0.f, za_y = 0.f, za_z = 0.f, za_w = 0.f;
  float zb_x = 0.f, zb_y = 0.f, zb_z = 0.f, zb_w = 0.f;
  int hme = lane >> 3;
  unsigned lane4 = lane << 2;
  const char* hbc = (const char*)hb;
  v2f acc = {0.f, 0.f};
  for (int base = row; base < end; base += 64) {
    int cnt = min(64, end - base);
    if (lane < cnt) {
      int s = csr[base + lane];
      sidx[w][lane] = s << 8;            // byte offset into hb (64 words/row)
      float4 pa = *(const float4*)&ssrc[(size_t)s * 8];
      float4 pb = *(const float4*)&ssrc[(size_t)s * 8 + 4];
      float4 ea, eb;
      ea.x = __expf(lrelu(pa.x + sda.x)); ea.y = __expf(lrelu(pa.y + sda.y));
      ea.z = __expf(lrelu(pa.z + sda.z)); ea.w = __expf(lrelu(pa.w + sda.w));
      eb.x = __expf(lrelu(pb.x + sdb.x)); eb.y = __expf(lrelu(pb.y + sdb.y));
      eb.z = __expf(lrelu(pb.z + sdb.z)); eb.w = __expf(lrelu(pb.w + sdb.w));
      za_x += ea.x; za_y += ea.y; za_z += ea.z; za_w += ea.w;
      zb_x += eb.x; zb_y += eb.y; zb_z += eb.z; zb_w += eb.w;
      *(float4*)&sexp[w][lane][0] = ea;
      *(float4*)&sexp[w][lane][4] = eb;
    }
    wave_fence();
    int g = 0;
    for (; g + 8 <= cnt; g += 8) {
      unsigned off[8];
      *(int4*)&off[0] = *(const int4*)&sidx[w][g];
      *(int4*)&off[4] = *(const int4*)&sidx[w][g + 4];
      unsigned uv[8];
#pragma unroll
      for (int j = 0; j < 8; ++j)
        uv[j] = *(const unsigned*)(hbc + (off[j] | lane4));   // 8 gathers in flight
#pragma unroll
      for (int j = 0; j < 8; ++j) {
        float a = sexp[w][g + j][hme];
        float2 vf = unpack_bf2(uv[j]);
        v2f v = {vf.x, vf.y};
        acc += a * v;
      }
    }
    for (; g < cnt; ++g) {
      unsigned off = (unsigned)sidx[w][g];
      unsigned uvr = *(const unsigned*)(hbc + (off | lane4));
      float a = sexp[w][g][hme];
      float2 vf = unpack_bf2(uvr);
      v2f v = {vf.x, vf.y};
      acc += a * v;
    }
    wave_fence();
  }
#pragma unroll
  for (int off = 32; off; off >>= 1) {
    za_x += __shfl_xor(za_x, off); za_y += __shfl_xor(za_y, off);
    za_z += __shfl_xor(za_z, off); za_w += __shfl_xor(za_w, off);
    zb_x += __shfl_xor(zb_x, off); zb_y += __shfl_xor(zb_y, off);
    zb_z += __shfl_xor(zb_z, off); zb_w += __shfl_xor(zb_w, off);
  }
  float zh[8] = {za_x, za_y, za_z, za_w, zb_x, zb_y, zb_z, zb_w};
  float z = zh[hme];
  float iz = z > 0.f ? 1.f / z : 0.f;
  *(float2*)&out[(size_t)n * 128 + lane * 2] = make_float2(acc.x * iz, acc.y * iz);
}

// ---------------- hetero-mean + bias + ELU (layer 1), writes fp32 + packed bf16 ----------------
__global__ void combine1_k(const float* __restrict__ oa, const float* __restrict__ ob,
                           const float* __restrict__ b1, float* __restrict__ hmid,
                           unsigned* __restrict__ hmidb) {
  int idx = blockIdx.x * 256 + threadIdx.x;
  if (idx >= NN * 64) return;
  int n = idx >> 6, j2 = idx & 63, j = j2 * 2;
  float2 va = *(const float2*)&oa[(size_t)n * 128 + j];
  float2 vb = *(const float2*)&ob[(size_t)n * 128 + j];
  float vx = 0.5f * ((va.x + b1[j]) + (vb.x + b1[128 + j]));
  float vy = 0.5f * ((va.y + b1[j + 1]) + (vb.y + b1[128 + j + 1]));
  vx = vx > 0.f ? vx : (__expf(vx) - 1.f);
  vy = vy > 0.f ? vy : (__expf(vy) - 1.f);
  *(float2*)&hmid[(size_t)n * 128 + j] = make_float2(vx, vy);
  hmidb[idx] = pack_bf2(vx, vy);
}

// ---------------- layer-2 folds ----------------
__global__ void fold2_k(const float* __restrict__ W2, const float* __restrict__ a2s,
                        const float* __restrict__ a2d, float* __restrict__ wsf,
                        float* __restrict__ wdf) {
  int idx = blockIdx.x * 256 + threadIdx.x;
  if (idx >= 2048) return;
  int t = idx >> 10, r = idx & 1023, hh = r >> 7, k = r & 127;
  const float* wrow = W2 + (size_t)t * 65536 + (size_t)k * 512 + hh * 64;
  const float* as = a2s + t * 512 + hh * 64;
  const float* ad = a2d + t * 512 + hh * 64;
  float s1 = 0.f, s2 = 0.f;
  for (int c = 0; c < 64; ++c) { s1 += wrow[c] * as[c]; s2 += wrow[c] * ad[c]; }
  wsf[idx] = s1; wdf[idx] = s2;
}

// fold W2 into transposed, bf16-packed MFMA B operand: BTp[t][col 64][k 1024 (512 words)]
__global__ void foldBT_k(const float* __restrict__ W2, unsigned* __restrict__ BTp) {
  int idx = blockIdx.x * 256 + threadIdx.x;
  if (idx >= 65536) return;
  int t = idx >> 15, r = idx & 32767, c = r >> 9, kw = r & 511;
  int K0 = kw * 2, K1 = K0 + 1;
  int hh0 = K0 >> 7, kk0 = K0 & 127;
  int hh1 = K1 >> 7, kk1 = K1 & 127;
  float v0 = 0.125f * W2[(size_t)t * 65536 + (size_t)kk0 * 512 + hh0 * 64 + c];
  float v1 = 0.125f * W2[(size_t)t * 65536 + (size_t)kk1 * 512 + hh1 * 64 + c];
  BTp[idx] = pack_bf2(v0, v1);
}

// ---------------- layer-2 scores from hmid ----------------
__global__ void score2_k(const float* __restrict__ hmid, const float* __restrict__ wsf,
                         const float* __restrict__ wdf, float* __restrict__ ss,
                         float* __restrict__ sdo) {
  int idx = blockIdx.x * 256 + threadIdx.x;
  if (idx >= NN * 8) return;
  int n = idx >> 3, hh = idx & 7;
  const float* hm = hmid + (size_t)n * 128;
  const float* w0s = wsf + (size_t)hh * 128;
  const float* w0d = wdf + (size_t)hh * 128;
  const float* w1s = wsf + (size_t)(8 + hh) * 128;
  const float* w1d = wdf + (size_t)(8 + hh) * 128;
  float s0s = 0.f, s0d = 0.f, s1s = 0.f, s1d = 0.f;
#pragma unroll
  for (int c = 0; c < 128; c += 4) {
    float4 f = *(const float4*)&hm[c];
    float4 a = *(const float4*)&w0s[c];
    float4 b = *(const float4*)&w0d[c];
    float4 u = *(const float4*)&w1s[c];
    float4 v = *(const float4*)&w1d[c];
    s0s += f.x * a.x + f.y * a.y + f.z * a.z + f.w * a.w;
    s0d += f.x * b.x + f.y * b.y + f.z * b.z + f.w * b.w;
    s1s += f.x * u.x + f.y * u.y + f.z * u.z + f.w * u.w;
    s1d += f.x * v.x + f.y * v.y + f.z * v.z + f.w * v.w;
  }
  ss[idx] = s0s; sdo[idx] = s0d;
  ss[NN * 8 + idx] = s1s; sdo[NN * 8 + idx] = s1d;
}

// ---------------- layer-2 aggregation: wave per node, both types, 8-deep pipelined gather ----------------
__global__ __launch_bounds__(256) void aggw2_k(const int* __restrict__ rowptr,
                                               const int* __restrict__ csr,
                                               const float* __restrict__ ssrc,
                                               const float* __restrict__ sdst,
                                               const unsigned* __restrict__ hmidb,
                                               unsigned* __restrict__ aggp) {
  int t = blockIdx.y;
  rowptr += t * (NN + 1); csr += (size_t)t * EE;
  ssrc += (size_t)t * NN * 8; sdst += (size_t)t * NN * 8;
  aggp += (size_t)t * NN * 512;
  int tid = threadIdx.x, w = tid >> 6, lane = tid & 63;
  int n = blockIdx.x * 4 + w;
  int row = rowptr[n], end = rowptr[n + 1];
  __shared__ __align__(16) int sidx[4][64];
  __shared__ __align__(16) float sexp[4][64][8];
  float4 sda = *(const float4*)&sdst[(size_t)n * 8];
  float4 sdb = *(const float4*)&sdst[(size_t)n * 8 + 4];
  float za_x = 0.f, za_y = 0.f, za_z = 0.f, za_w = 0.f;
  float zb_x = 0.f, zb_y = 0.f, zb_z = 0.f, zb_w = 0.f;
  unsigned lane4 = lane << 2;
  const char* hbc = (const char*)hmidb;
  v2f acc[8];
#pragma unroll
  for (int i = 0; i < 8; ++i) acc[i] = (v2f){0.f, 0.f};
  for (int base = row; base < end; base += 64) {
    int cnt = min(64, end - base);
    if (lane < cnt) {
      int s = csr[base + lane];
      sidx[w][lane] = s << 8;            // byte offset into hmidb
      float4 pa = *(const float4*)&ssrc[(size_t)s * 8];
      float4 pb = *(const float4*)&ssrc[(size_t)s * 8 + 4];
      float4 ea, eb;
      ea.x = __expf(lrelu(pa.x + sda.x)); ea.y = __expf(lrelu(pa.y + sda.y));
      ea.z = __expf(lrelu(pa.z + sda.z)); ea.w = __expf(lrelu(pa.w + sda.w));
      eb.x = __expf(lrelu(pb.x + sdb.x)); eb.y = __expf(lrelu(pb.y + sdb.y));
      eb.z = __expf(lrelu(pb.z + sdb.z)); eb.w = __expf(lrelu(pb.w + sdb.w));
      za_x += ea.x; za_y += ea.y; za_z += ea.z; za_w += ea.w;
      zb_x += eb.x; zb_y += eb.y; zb_z += eb.z; zb_w += eb.w;
      *(float4*)&sexp[w][lane][0] = ea;
      *(float4*)&sexp[w][lane][4] = eb;
    }
    wave_fence();
    int g = 0;
    for (; g + 8 <= cnt; g += 8) {
      unsigned off[8];
      *(int4*)&off[0] = *(const int4*)&sidx[w][g];
      *(int4*)&off[4] = *(const int4*)&sidx[w][g + 4];
      unsigned uv[8];
#pragma unroll
      for (int j = 0; j < 8; ++j)
        uv[j] = *(const unsigned*)(hbc + (off[j] | lane4));   // 8 gathers in flight
#pragma unroll
      for (int j = 0; j < 8; ++j) {
        float4 ea = *(const float4*)&sexp[w][g + j][0];
        float4 eb = *(const float4*)&sexp[w][g + j][4];
        float2 vf = unpack_bf2(uv[j]);
        v2f v = {vf.x, vf.y};
        acc[0] += ea.x * v;
        acc[1] += ea.y * v;
        acc[2] += ea.z * v;
        acc[3] += ea.w * v;
        acc[4] += eb.x * v;
        acc[5] += eb.y * v;
        acc[6] += eb.z * v;
        acc[7] += eb.w * v;
      }
    }
    for (; g < cnt; ++g) {
      unsigned off = (unsigned)sidx[w][g];
      unsigned uvr = *(const unsigned*)(hbc + (off | lane4));
      float4 ea = *(const float4*)&sexp[w][g][0];
      float4 eb = *(const float4*)&sexp[w][g][4];
      float2 vf = unpack_bf2(uvr);
      v2f v = {vf.x, vf.y};
      acc[0] += ea.x * v;
      acc[1] += ea.y * v;
      acc[2] += ea.z * v;
      acc[3] += ea.w * v;
      acc[4] += eb.x * v;
      acc[5] += eb.y * v;
      acc[6] += eb.z * v;
      acc[7] += eb.w * v;
    }
    wave_fence();
  }
#pragma unroll
  for (int off = 32; off; off >>= 1) {
    za_x += __shfl_xor(za_x, off); za_y += __shfl_xor(za_y, off);
    za_z += __shfl_xor(za_z, off); za_w += __shfl_xor(za_w, off);
    zb_x += __shfl_xor(zb_x, off); zb_y += __shfl_xor(zb_y, off);
    zb_z += __shfl_xor(zb_z, off); zb_w += __shfl_xor(zb_w, off);
  }
  float zh[8] = {za_x, za_y, za_z, za_w, zb_x, zb_y, zb_z, zb_w};
#pragma unroll
  for (int i = 0; i < 8; ++i) {
    float z = zh[i];
    float iz = z > 0.f ? 1.f / z : 0.f;
    aggp[(size_t)n * 512 + i * 64 + lane] = pack_bf2(acc[i].x * iz, acc[i].y * iz);
  }
}

// ---------------- layer-2 GEMM via MFMA: feat = ELU(0.5*(Aa*Ba + Ab*Bb + ba + bb)) ----------------
__global__ __launch_bounds__(256) void gemm2_k(const unsigned* __restrict__ Ap,
                                               const unsigned* __restrict__ BT,
                                               const float* __restrict__ b2,
                                               float* __restrict__ feat) {
  int tid = threadIdx.x, w = tid >> 6, l = tid & 63;
  int lr = l & 15, lgq = l >> 4;
  int rowbase = blockIdx.x * 64 + w * 16;
  int arow = rowbase + lr;
  if (arow > NN - 1) arow = NN - 1;   // clamp: garbage-free load, store is guarded
  f32x4 acc0 = {0.f, 0.f, 0.f, 0.f}, acc1 = acc0, acc2 = acc0, acc3 = acc0;
#pragma unroll
  for (int t = 0; t < 2; ++t) {
    const unsigned* ap = Ap + (size_t)t * NN * 512 + (size_t)arow * 512 + lgq * 4;
    const unsigned* bp = BT + t * 32768 + lr * 512 + lgq * 4;
    for (int kw = 0; kw < 512; kw += 16) {   // 32 k-elements per step
      uint4 av = *(const uint4*)(ap + kw);
      uint4 bv0 = *(const uint4*)(bp + kw);
      uint4 bv1 = *(const uint4*)(bp + 16 * 512 + kw);
      uint4 bv2 = *(const uint4*)(bp + 32 * 512 + kw);
      uint4 bv3 = *(const uint4*)(bp + 48 * 512 + kw);
      bf16x8 afq = *(const bf16x8*)&av;
      acc0 = __builtin_amdgcn_mfma_f32_16x16x32_bf16(afq, *(const bf16x8*)&bv0, acc0, 0, 0, 0);
      acc1 = __builtin_amdgcn_mfma_f32_16x16x32_bf16(afq, *(const bf16x8*)&bv1, acc1, 0, 0, 0);
      acc2 = __builtin_amdgcn_mfma_f32_16x16x32_bf16(afq, *(const bf16x8*)&bv2, acc2, 0, 0, 0);
      acc3 = __builtin_amdgcn_mfma_f32_16x16x32_bf16(afq, *(const bf16x8*)&bv3, acc3, 0, 0, 0);
    }
  }
  f32x4 accs[4] = {acc0, acc1, acc2, acc3};
#pragma unroll
  for (int ct = 0; ct < 4; ++ct) {
    int col = ct * 16 + lr;
    float bsum = b2[col] + b2[64 + col];
#pragma unroll
    for (int r = 0; r < 4; ++r) {
      int rowq = rowbase + lgq * 4 + r;
      if (rowq < NN) {
        float v = 0.5f * (accs[ct][r] + bsum);
        v = v > 0.f ? v : (__expf(v) - 1.f);
        feat[(size_t)rowq * 64 + col] = v;
      }
    }
  }
}

// ---------------- classifier ----------------
__global__ __launch_bounds__(256) void cls_k(const float* __restrict__ feat,
                                             const float* __restrict__ Wc1,
                                             const float* __restrict__ bc1,
                                             const float* __restrict__ Wc2,
                                             const float* __restrict__ bc2,
                                             float* __restrict__ out) {
  __shared__ float w1[64 * 32];
  __shared__ float w2[64];
  __shared__ float b1s[32], b2s[2];
  __shared__ float fs[8 * 64];
  __shared__ float hs[8 * 32];
  int tid = threadIdx.x;
  for (int i = tid; i < 2048; i += 256) w1[i] = Wc1[i];
  if (tid < 64) w2[tid] = Wc2[tid];
  if (tid < 32) b1s[tid] = bc1[tid];
  if (tid < 2) b2s[tid] = bc2[tid];
  int nbase = blockIdx.x * 8;
  for (int i = tid; i < 512; i += 256) fs[i] = feat[(size_t)nbase * 64 + i];
  __syncthreads();
  int local = tid >> 5, tt = tid & 31;
  const float* f = fs + local * 64;
  float acc = b1s[tt];
#pragma unroll
  for (int c = 0; c < 64; ++c) acc += f[c] * w1[c * 32 + tt];
  hs[local * 32 + tt] = fmaxf(acc, 0.f);
  __syncthreads();
  if (tid < 16) {
    int l = tid >> 1, j = tid & 1;
    float o = b2s[j];
#pragma unroll
    for (int i = 0; i < 32; ++i) o += hs[l * 32 + i] * w2[i * 2 + j];
    out[(size_t)(nbase + l) * 2 + j] = o;
  }
}

extern "C" void kernel_launch(void* const* d_in, const int* in_sizes, int n_in,
                              void* d_out, int out_size, void* d_ws, size_t ws_size,
                              hipStream_t stream) {
  const float* x   = (const float*)d_in[0];
  const int* eia   = (const int*)d_in[1];
  const int* eib   = (const int*)d_in[2];
  const float* W1  = (const float*)d_in[3];
  const float* a1s = (const float*)d_in[4];
  const float* a1d = (const float*)d_in[5];
  const float* b1  = (const float*)d_in[6];
  const float* W2  = (const float*)d_in[7];
  const float* a2s = (const float*)d_in[8];
  const float* a2d = (const float*)d_in[9];
  const float* b2  = (const float*)d_in[10];
  const float* Wc1 = (const float*)d_in[11];
  const float* bc1 = (const float*)d_in[12];
  const float* Wc2 = (const float*)d_in[13];
  const float* bc2 = (const float*)d_in[14];
  float* out = (float*)d_out;

  char* ws = (char*)d_ws;
  size_t off = 0;
  auto alloc = [&](size_t bytes) -> char* {
    char* p = ws + off;
    off += (bytes + 255) & ~(size_t)255;
    return p;
  };
  int* gcnt       = (int*)alloc((size_t)2 * NB * 4);
  int* bstart     = (int*)alloc((size_t)2 * NB * 4);
  int* bbuf       = (int*)alloc((size_t)2 * NB * BCAP * 4);
  int* rowptr     = (int*)alloc((size_t)2 * (NN + 1) * 4);
  int* csr        = (int*)alloc((size_t)2 * EE * 4);
  unsigned* h1b   = (unsigned*)alloc((size_t)2 * NN * 64 * 4);
  float* s1s      = (float*)alloc((size_t)2 * NN * 8 * 4);
  float* s1d      = (float*)alloc((size_t)2 * NN * 8 * 4);
  float* o1       = (float*)alloc((size_t)2 * NN * 128 * 4);
  float* hmid     = (float*)alloc((size_t)NN * 128 * 4);
  unsigned* hmidb = (unsigned*)alloc((size_t)NN * 64 * 4);
  float* wsf      = (float*)alloc((size_t)2048 * 4);
  float* wdf      = (float*)alloc((size_t)2048 * 4);
  unsigned* BTp   = (unsigned*)alloc((size_t)65536 * 4);   // bf16-packed transposed fold
  float* s2s      = (float*)alloc((size_t)2 * NN * 8 * 4);
  float* s2d      = (float*)alloc((size_t)2 * NN * 8 * 4);
  unsigned* aggp  = (unsigned*)alloc((size_t)2 * NN * 512 * 4);  // bf16-packed agg, both types
  float* feat     = (float*)alloc((size_t)NN * 64 * 4);

  // CSR build: bucketed two-pass (grid-strided binning, packed entries)
  hipMemsetAsync(gcnt, 0, (size_t)2 * NB * 4, stream);
  bin_k<<<dim3(NBLK, 2), 256, 0, stream>>>(eia, eib, gcnt, bbuf);
  bscan_k<<<1, 512, 0, stream>>>(gcnt, bstart);
  build_k<<<dim3(NB, 2), 256, 0, stream>>>(gcnt, bstart, bbuf, rowptr, csr);

  // layer-2 weight folds (independent of layer 1; launch early)
  fold2_k<<<8, 256, 0, stream>>>(W2, a2s, a2d, wsf, wdf);
  foldBT_k<<<256, 256, 0, stream>>>(W2, BTp);

  // layer 1: GEMM writes ONLY packed bf16 h1b (fp32 C dropped); scores from h1b
  sgemm_k<256, 64, 64, 32, 4, 4><<<dim3((NN + 63) / 64, 2, 2), 256, 0, stream>>>(
      x, W1, nullptr, NN, 128, 256, 0LL, 256LL * 128, 0LL, h1b, (long long)NN * 64);
  scoreb_k<<<(2 * NN * 8 + 255) / 256, 256, 0, stream>>>(h1b, a1s, a1d, s1s, s1d);
  aggw1_k<<<dim3(NN / 4, 2), 256, 0, stream>>>(rowptr, csr, s1s, s1d, h1b, o1);
  combine1_k<<<(NN * 64 + 255) / 256, 256, 0, stream>>>(o1, o1 + (size_t)NN * 128, b1, hmid, hmidb);

  // layer 2: scores, merged both-type aggregation (bf16 out), fused MFMA GEMM + combine + ELU
  score2_k<<<(NN * 8 + 255) / 256, 256, 0, stream>>>(hmid, wsf, wdf, s2s, s2d);
  aggw2_k<<<dim3(NN / 4, 2), 256, 0, stream>>>(rowptr, csr, s2s, s2d, hmidb, aggp);
  gemm2_k<<<(NN + 63) / 64, 256, 0, stream>>>(aggp, BTp, b2, feat);

  // classifier
  cls_k<<<NN / 8, 256, 0, stream>>>(feat, Wc1, bc1, Wc2, bc2, out);
}